// Round 1
// baseline (3014.380 us; speedup 1.0000x reference)
//
#include <hip/hip_runtime.h>

typedef float f4 __attribute__((ext_vector_type(4)));

#define G_TAB 8192
#define TG 32

__device__ __forceinline__ float lrelu(float x) { return x > 0.f ? x : 0.015f * x; }

// v[i][:] = emb[z[i]][:]
__global__ __launch_bounds__(256) void gather_emb(const int* __restrict__ z,
    const float* __restrict__ emb, float* __restrict__ v, int nf4) {
  int i = blockIdx.x * 256 + threadIdx.x;
  if (i >= nf4) return;
  int a = i >> 5, s = i & 31;
  ((f4*)v)[i] = ((const f4*)emb)[z[a] * 32 + s];
}

// per-edge distance d, cutoff C, and degree(col) counts
__global__ __launch_bounds__(256) void edge_geom(const int* __restrict__ ei,
    const float* __restrict__ pos, float* __restrict__ ed, float* __restrict__ ec,
    float* __restrict__ deg, int E) {
  int e = blockIdx.x * 256 + threadIdx.x;
  if (e >= E) return;
  int r = ei[e], c = ei[E + e];
  float dx = pos[3*r] - pos[3*c];
  float dy = pos[3*r+1] - pos[3*c+1];
  float dz = pos[3*r+2] - pos[3*c+2];
  float d = sqrtf(dx*dx + dy*dy + dz*dz);
  ed[e] = d;
  ec[e] = 0.5f * (cosf(d * 0.6283185307179586f) + 1.0f);
  atomicAdd(&deg[c], 1.0f);
}

// w = lout_w + I
__global__ __launch_bounds__(256) void make_loutI(const float* __restrict__ lw,
    float* __restrict__ w) {
  int i = blockIdx.x * 256 + threadIdx.x;  // 16384 total
  int k = i >> 7, j = i & 127;
  w[i] = lw[i] + (k == j ? 1.0f : 0.0f);
}

// Tabulate T(d) = MLP3(MLP2(MLP1(gauss(d)))) on a G_TAB grid. One block = TG points.
__global__ __launch_bounds__(256) void build_table(
    const float* __restrict__ w1, const float* __restrict__ b1,
    const float* __restrict__ w2, const float* __restrict__ b2,
    const float* __restrict__ w3, const float* __restrict__ b3,
    float* __restrict__ table) {
  __shared__ float wbuf[128 * 128];
  __shared__ float hA[TG * 128];
  __shared__ float hB[TG * 128];
  __shared__ float demb[TG * 52];
  int tid = threadIdx.x;
  int g0 = blockIdx.x * TG;
  const float delta = 5.0f / (G_TAB - 1);
  for (int i = tid; i < TG * 50; i += 256) {
    int p = i / 50, k = i - p * 50;
    float d = (g0 + p) * delta;
    float t = d - k * (5.0f / 49.0f);
    demb[p * 52 + k] = expf(-48.02f * t * t);  // coeff = -0.5/(5/49)^2
  }
  for (int i = tid; i < 1600; i += 256) ((f4*)wbuf)[i] = ((const f4*)w1)[i];
  __syncthreads();
  int cg = tid & 31, pl = tid >> 5;
  int j0 = cg * 4;
  f4 acc[4];
  // h1 = lrelu(demb @ w1 + b1)
  {
    f4 bb = *(const f4*)&b1[j0];
    #pragma unroll
    for (int p = 0; p < 4; p++) acc[p] = (f4)0.f;
    for (int k = 0; k < 50; k++) {
      f4 w = *(f4*)&wbuf[k * 128 + j0];
      #pragma unroll
      for (int p = 0; p < 4; p++) acc[p] += demb[(pl * 4 + p) * 52 + k] * w;
    }
    #pragma unroll
    for (int p = 0; p < 4; p++) {
      f4 x = acc[p] + bb;
      #pragma unroll
      for (int c = 0; c < 4; c++) x[c] = lrelu(x[c]);
      *(f4*)&hA[(pl * 4 + p) * 128 + j0] = x;
    }
  }
  __syncthreads();
  for (int i = tid; i < 4096; i += 256) ((f4*)wbuf)[i] = ((const f4*)w2)[i];
  __syncthreads();
  // h2 = lrelu(h1 @ w2 + b2)
  {
    f4 bb = *(const f4*)&b2[j0];
    #pragma unroll
    for (int p = 0; p < 4; p++) acc[p] = (f4)0.f;
    for (int k = 0; k < 128; k++) {
      f4 w = *(f4*)&wbuf[k * 128 + j0];
      #pragma unroll
      for (int p = 0; p < 4; p++) acc[p] += hA[(pl * 4 + p) * 128 + k] * w;
    }
    #pragma unroll
    for (int p = 0; p < 4; p++) {
      f4 x = acc[p] + bb;
      #pragma unroll
      for (int c = 0; c < 4; c++) x[c] = lrelu(x[c]);
      *(f4*)&hB[(pl * 4 + p) * 128 + j0] = x;
    }
  }
  __syncthreads();
  for (int i = tid; i < 4096; i += 256) ((f4*)wbuf)[i] = ((const f4*)w3)[i];
  __syncthreads();
  // T = h2 @ w3 + b3   (no act, no C — C is applied per edge)
  {
    f4 bb = *(const f4*)&b3[j0];
    #pragma unroll
    for (int p = 0; p < 4; p++) acc[p] = (f4)0.f;
    for (int k = 0; k < 128; k++) {
      f4 w = *(f4*)&wbuf[k * 128 + j0];
      #pragma unroll
      for (int p = 0; p < 4; p++) acc[p] += hB[(pl * 4 + p) * 128 + k] * w;
    }
    #pragma unroll
    for (int p = 0; p < 4; p++)
      *(f4*)&table[(size_t)(g0 + pl * 4 + p) * 128 + j0] = acc[p] + bb;
  }
}

// out[Mx128] = op(A[Mx128] @ W[128x128] + bias)   M multiple of 32
// BIASMODE: 0 none, 1 +bias[j], 2 +rs[i]*bias[j].  ACT: lrelu. ACC: out += result.
template<int ACT, int ACC, int BIASMODE>
__global__ __launch_bounds__(256) void gemm128(
    const float* __restrict__ A, const float* __restrict__ W,
    const float* __restrict__ bias, const float* __restrict__ rs,
    float* __restrict__ out) {
  __shared__ float Ws[128 * 128];
  __shared__ float As[32 * 128];
  int tid = threadIdx.x;
  #pragma unroll
  for (int i = 0; i < 16; i++) ((f4*)Ws)[tid + 256 * i] = ((const f4*)W)[tid + 256 * i];
  size_t row0 = (size_t)blockIdx.x * 32;
  const f4* A4 = (const f4*)(A + row0 * 128);
  #pragma unroll
  for (int i = 0; i < 4; i++) ((f4*)As)[tid + 256 * i] = A4[tid + 256 * i];
  __syncthreads();
  int cg = tid & 31, rg = tid >> 5;
  int j0 = cg * 4, r0 = rg * 4;
  f4 acc[4];
  #pragma unroll
  for (int r = 0; r < 4; r++) acc[r] = (f4)0.f;
  for (int k = 0; k < 128; k += 4) {
    f4 a[4], w[4];
    #pragma unroll
    for (int r = 0; r < 4; r++) a[r] = *(f4*)&As[(r0 + r) * 128 + k];
    #pragma unroll
    for (int kk = 0; kk < 4; kk++) w[kk] = *(f4*)&Ws[(k + kk) * 128 + j0];
    #pragma unroll
    for (int r = 0; r < 4; r++)
      #pragma unroll
      for (int kk = 0; kk < 4; kk++)
        acc[r] += a[r][kk] * w[kk];
  }
  #pragma unroll
  for (int r = 0; r < 4; r++) {
    size_t grow = row0 + r0 + r;
    f4 x = acc[r];
    if (BIASMODE == 1) x += *(const f4*)&bias[j0];
    if (BIASMODE == 2) x += rs[grow] * (*(const f4*)&bias[j0]);
    if (ACT) {
      #pragma unroll
      for (int c = 0; c < 4; c++) x[c] = lrelu(x[c]);
    }
    f4* op = (f4*)&out[grow * 128 + j0];
    if (ACC) x += *op;
    *op = x;
  }
}

// S[col] += vlin[row] * lerp(table, d) * C   — 32 lanes (4 cols each) per edge
__global__ __launch_bounds__(256) void edge_scatter(
    const int* __restrict__ ei, const float* __restrict__ ed, const float* __restrict__ ec,
    const float* __restrict__ vlin, const float* __restrict__ table,
    float* __restrict__ S, int E) {
  int tid = threadIdx.x;
  int lane = tid & 31, grp = tid >> 5;
  int e = blockIdx.x * 8 + grp;
  if (e >= E) return;
  int r = ei[e], c = ei[E + e];
  float d = ed[e], cc = ec[e];
  const float sc = (float)(G_TAB - 1) / 5.0f;
  float u = d * sc;
  int i0 = (int)u;
  if (i0 > G_TAB - 2) i0 = G_TAB - 2;
  float f = u - (float)i0;
  int j0 = lane * 4;
  f4 t0 = *(const f4*)&table[(size_t)i0 * 128 + j0];
  f4 t1 = *(const f4*)&table[(size_t)i0 * 128 + 128 + j0];
  f4 vl = *(const f4*)&vlin[(size_t)r * 128 + j0];
  f4 val = vl * ((t0 + f * (t1 - t0)) * cc);
  float* Sp = &S[(size_t)c * 128 + j0];
  atomicAdd(Sp + 0, val[0]);
  atomicAdd(Sp + 1, val[1]);
  atomicAdd(Sp + 2, val[2]);
  atomicAdd(Sp + 3, val[3]);
}

// per-atom u = lrelu(v@u_w1+b1)@u_w2+b2 ; per-graph mean of u. 256 threads = 2 graphs? No:
// one thread per atom, block = 256 atoms = 2 graphs; reduce halves.
__global__ __launch_bounds__(256, 1) void readout(
    const float* __restrict__ v, const float* __restrict__ uw1,
    const float* __restrict__ ub1, const float* __restrict__ uw2,
    const float* __restrict__ ub2, float* __restrict__ out) {
  __shared__ float wt[64 * 128];  // transposed u_w1: wt[m][k]
  __shared__ float red[256];
  int tid = threadIdx.x;
  for (int i = tid; i < 8192; i += 256) {
    int m = i >> 7, k = i & 127;
    wt[i] = uw1[k * 64 + m];
  }
  __syncthreads();
  size_t a = (size_t)blockIdx.x * 256 + tid;
  f4 row[32];
  #pragma unroll
  for (int i = 0; i < 32; i++) row[i] = *(const f4*)&v[a * 128 + i * 4];
  float pa = 0.f;
  for (int m = 0; m < 64; m++) {
    float dot = ub1[m];
    #pragma unroll
    for (int i = 0; i < 32; i++) {
      f4 w = *(f4*)&wt[m * 128 + i * 4];
      dot += row[i][0] * w[0] + row[i][1] * w[1] + row[i][2] * w[2] + row[i][3] * w[3];
    }
    pa += lrelu(dot) * uw2[m];
  }
  red[tid] = pa;
  __syncthreads();
  for (int s = 64; s > 0; s >>= 1) {
    if ((tid & 127) < s) red[tid] += red[tid + s];
    __syncthreads();
  }
  if ((tid & 127) == 0) out[blockIdx.x * 2 + (tid >> 7)] = red[tid] * (1.0f / 128.0f) + ub2[0];
}

extern "C" void kernel_launch(void* const* d_in, const int* in_sizes, int n_in,
                              void* d_out, int out_size, void* d_ws, size_t ws_size,
                              hipStream_t stream) {
  const int*   z     = (const int*)d_in[0];
  const float* pos   = (const float*)d_in[1];
  const int*   ei    = (const int*)d_in[3];
  const float* emb   = (const float*)d_in[4];
  const float* w_lin = (const float*)d_in[5];
  const float* mw1   = (const float*)d_in[6];
  const float* mb1   = (const float*)d_in[7];
  const float* mw2   = (const float*)d_in[8];
  const float* mb2   = (const float*)d_in[9];
  const float* mw3   = (const float*)d_in[10];
  const float* mb3   = (const float*)d_in[11];
  const float* loutw = (const float*)d_in[12];
  const float* loutb = (const float*)d_in[13];
  const float* vw1   = (const float*)d_in[14];
  const float* vb1   = (const float*)d_in[15];
  const float* vw2   = (const float*)d_in[16];
  const float* vb2   = (const float*)d_in[17];
  const float* uw1   = (const float*)d_in[18];
  const float* ub1   = (const float*)d_in[19];
  const float* uw2   = (const float*)d_in[20];
  const float* ub2   = (const float*)d_in[21];
  int N = in_sizes[0];
  int E = in_sizes[3] / 2;
  float* out = (float*)d_out;

  size_t off = 0;
  auto alloc = [&](size_t bytes) -> float* {
    float* p = (float*)((char*)d_ws + off);
    off += (bytes + 255) & ~(size_t)255;
    return p;
  };
  float* v     = alloc((size_t)N * 128 * 4);
  float* bufA  = alloc((size_t)N * 128 * 4);
  float* bufB  = alloc((size_t)N * 128 * 4);
  float* table = alloc((size_t)G_TAB * 128 * 4);
  float* loutI = alloc(128 * 128 * 4);
  float* deg   = alloc((size_t)N * 4);
  float* ed    = alloc((size_t)E * 4);
  float* ec    = alloc((size_t)E * 4);

  hipMemsetAsync(deg, 0, (size_t)N * 4, stream);
  gather_emb<<<(N * 32 + 255) / 256, 256, 0, stream>>>(z, emb, v, N * 32);
  edge_geom<<<(E + 255) / 256, 256, 0, stream>>>(ei, pos, ed, ec, deg, E);

  for (int l = 0; l < 3; l++) {
    make_loutI<<<64, 256, 0, stream>>>(loutw + (size_t)l * 16384, loutI);
    build_table<<<G_TAB / TG, 256, 0, stream>>>(
        mw1 + (size_t)l * 6400, mb1 + (size_t)l * 128,
        mw2 + (size_t)l * 16384, mb2 + (size_t)l * 128,
        mw3 + (size_t)l * 16384, mb3 + (size_t)l * 128, table);
    // vlin = v @ w_lin
    gemm128<0, 0, 0><<<N / 32, 256, 0, stream>>>(v, w_lin + (size_t)l * 16384,
                                                 nullptr, nullptr, bufA);
    hipMemsetAsync(bufB, 0, (size_t)N * 128 * 4, stream);
    edge_scatter<<<(E + 7) / 8, 256, 0, stream>>>(ei, ed, ec, bufA, table, bufB, E);
    // agg = S @ (lout+I) + deg*lout_b
    gemm128<0, 0, 2><<<N / 32, 256, 0, stream>>>(bufB, loutI, loutb + (size_t)l * 128,
                                                 deg, bufA);
    // t = lrelu(agg @ v_w1 + v_b1)
    gemm128<1, 0, 1><<<N / 32, 256, 0, stream>>>(bufA, vw1 + (size_t)l * 16384,
                                                 vb1 + (size_t)l * 128, nullptr, bufB);
    // v += t @ v_w2 + v_b2
    gemm128<0, 1, 1><<<N / 32, 256, 0, stream>>>(bufB, vw2 + (size_t)l * 16384,
                                                 vb2 + (size_t)l * 128, nullptr, v);
  }
  readout<<<N / 256, 256, 0, stream>>>(v, uw1, ub1, uw2, ub2, out);
}

// Round 2
// 520.460 us; speedup vs baseline: 5.7918x; 5.7918x over previous
//
#include <hip/hip_runtime.h>

typedef float f4 __attribute__((ext_vector_type(4)));

#define G_TAB 4096
#define TG 32

__device__ __forceinline__ float lrelu(float x) { return x > 0.f ? x : 0.015f * x; }

// v[i][:] = emb[z[i]][:]
__global__ __launch_bounds__(256) void gather_emb(const int* __restrict__ z,
    const float* __restrict__ emb, float* __restrict__ v, int nf4) {
  int i = blockIdx.x * 256 + threadIdx.x;
  if (i >= nf4) return;
  int a = i >> 5, s = i & 31;
  ((f4*)v)[i] = ((const f4*)emb)[z[a] * 32 + s];
}

// per-edge distance d and cutoff C
__global__ __launch_bounds__(256) void edge_geom(const int* __restrict__ ei,
    const float* __restrict__ pos, float* __restrict__ ed, float* __restrict__ ec,
    int E) {
  int e = blockIdx.x * 256 + threadIdx.x;
  if (e >= E) return;
  int r = ei[e], c = ei[E + e];
  float dx = pos[3*r] - pos[3*c];
  float dy = pos[3*r+1] - pos[3*c+1];
  float dz = pos[3*r+2] - pos[3*c+2];
  float d = sqrtf(dx*dx + dy*dy + dz*dz);
  ed[e] = d;
  ec[e] = 0.5f * (cosf(d * 0.6283185307179586f) + 1.0f);
}

// CSR row starts via binary search on sorted ei[0] (src-major edge order)
__global__ __launch_bounds__(256) void make_starts(const int* __restrict__ row,
    int* __restrict__ starts, int E, int N) {
  int i = blockIdx.x * 256 + threadIdx.x;
  if (i > N) return;
  int lo = 0, hi = E;
  while (lo < hi) { int mid = (lo + hi) >> 1; if (row[mid] < i) lo = mid + 1; else hi = mid; }
  starts[i] = lo;
}

// w = lout_w + I
__global__ __launch_bounds__(256) void make_loutI(const float* __restrict__ lw,
    float* __restrict__ w) {
  int i = blockIdx.x * 256 + threadIdx.x;  // 16384 total
  int k = i >> 7, j = i & 127;
  w[i] = lw[i] + (k == j ? 1.0f : 0.0f);
}

// c1[j] = sum_k lout_b[k] * v_w1[k][j]
__global__ __launch_bounds__(128) void make_c1(const float* __restrict__ lb,
    const float* __restrict__ w1, float* __restrict__ c1) {
  int j = threadIdx.x;
  float s = 0.f;
  for (int k = 0; k < 128; k++) s += lb[k] * w1[k * 128 + j];
  c1[j] = s;
}

// Tabulate T(d) = MLP3(MLP2(MLP1(gauss(d)))) on a G_TAB grid. One block = TG points.
__global__ __launch_bounds__(256) void build_table(
    const float* __restrict__ w1, const float* __restrict__ b1,
    const float* __restrict__ w2, const float* __restrict__ b2,
    const float* __restrict__ w3, const float* __restrict__ b3,
    float* __restrict__ table) {
  __shared__ float wbuf[128 * 128];
  __shared__ float hA[TG * 128];
  __shared__ float hB[TG * 128];
  __shared__ float demb[TG * 52];
  int tid = threadIdx.x;
  int g0 = blockIdx.x * TG;
  const float delta = 5.0f / (G_TAB - 1);
  for (int i = tid; i < TG * 50; i += 256) {
    int p = i / 50, k = i - p * 50;
    float d = (g0 + p) * delta;
    float t = d - k * (5.0f / 49.0f);
    demb[p * 52 + k] = expf(-48.02f * t * t);  // coeff = -0.5/(5/49)^2
  }
  for (int i = tid; i < 1600; i += 256) ((f4*)wbuf)[i] = ((const f4*)w1)[i];
  __syncthreads();
  int cg = tid & 31, pl = tid >> 5;
  int j0 = cg * 4;
  f4 acc[4];
  // h1 = lrelu(demb @ w1 + b1)
  {
    f4 bb = *(const f4*)&b1[j0];
    #pragma unroll
    for (int p = 0; p < 4; p++) acc[p] = (f4)0.f;
    for (int k = 0; k < 50; k++) {
      f4 w = *(f4*)&wbuf[k * 128 + j0];
      #pragma unroll
      for (int p = 0; p < 4; p++) acc[p] += demb[(pl * 4 + p) * 52 + k] * w;
    }
    #pragma unroll
    for (int p = 0; p < 4; p++) {
      f4 x = acc[p] + bb;
      #pragma unroll
      for (int c = 0; c < 4; c++) x[c] = lrelu(x[c]);
      *(f4*)&hA[(pl * 4 + p) * 128 + j0] = x;
    }
  }
  __syncthreads();
  for (int i = tid; i < 4096; i += 256) ((f4*)wbuf)[i] = ((const f4*)w2)[i];
  __syncthreads();
  // h2 = lrelu(h1 @ w2 + b2)
  {
    f4 bb = *(const f4*)&b2[j0];
    #pragma unroll
    for (int p = 0; p < 4; p++) acc[p] = (f4)0.f;
    for (int k = 0; k < 128; k++) {
      f4 w = *(f4*)&wbuf[k * 128 + j0];
      #pragma unroll
      for (int p = 0; p < 4; p++) acc[p] += hA[(pl * 4 + p) * 128 + k] * w;
    }
    #pragma unroll
    for (int p = 0; p < 4; p++) {
      f4 x = acc[p] + bb;
      #pragma unroll
      for (int c = 0; c < 4; c++) x[c] = lrelu(x[c]);
      *(f4*)&hB[(pl * 4 + p) * 128 + j0] = x;
    }
  }
  __syncthreads();
  for (int i = tid; i < 4096; i += 256) ((f4*)wbuf)[i] = ((const f4*)w3)[i];
  __syncthreads();
  // T = h2 @ w3 + b3   (no act, no C — C is applied per edge)
  {
    f4 bb = *(const f4*)&b3[j0];
    #pragma unroll
    for (int p = 0; p < 4; p++) acc[p] = (f4)0.f;
    for (int k = 0; k < 128; k++) {
      f4 w = *(f4*)&wbuf[k * 128 + j0];
      #pragma unroll
      for (int p = 0; p < 4; p++) acc[p] += hB[(pl * 4 + p) * 128 + k] * w;
    }
    #pragma unroll
    for (int p = 0; p < 4; p++)
      *(f4*)&table[(size_t)(g0 + pl * 4 + p) * 128 + j0] = acc[p] + bb;
  }
}

// out[Mx128] = op(A[Mx128] @ W[128x128] + bias)   M multiple of 32
// BIASMODE: 0 none, 1 +bias[j], 2 +rs[i]*bias[j], 3 +rs[i]*bias[j]+bias2[j].
// ACT: lrelu. ACC: out += result.
template<int ACT, int ACC, int BIASMODE>
__global__ __launch_bounds__(256) void gemm128(
    const float* __restrict__ A, const float* __restrict__ W,
    const float* __restrict__ bias, const float* __restrict__ bias2,
    const float* __restrict__ rs, float* __restrict__ out) {
  __shared__ float Ws[128 * 128];
  __shared__ float As[32 * 128];
  int tid = threadIdx.x;
  #pragma unroll
  for (int i = 0; i < 16; i++) ((f4*)Ws)[tid + 256 * i] = ((const f4*)W)[tid + 256 * i];
  size_t row0 = (size_t)blockIdx.x * 32;
  const f4* A4 = (const f4*)(A + row0 * 128);
  #pragma unroll
  for (int i = 0; i < 4; i++) ((f4*)As)[tid + 256 * i] = A4[tid + 256 * i];
  __syncthreads();
  int cg = tid & 31, rg = tid >> 5;
  int j0 = cg * 4, r0 = rg * 4;
  f4 acc[4];
  #pragma unroll
  for (int r = 0; r < 4; r++) acc[r] = (f4)0.f;
  for (int k = 0; k < 128; k += 4) {
    f4 a[4], w[4];
    #pragma unroll
    for (int r = 0; r < 4; r++) a[r] = *(f4*)&As[(r0 + r) * 128 + k];
    #pragma unroll
    for (int kk = 0; kk < 4; kk++) w[kk] = *(f4*)&Ws[(k + kk) * 128 + j0];
    #pragma unroll
    for (int r = 0; r < 4; r++)
      #pragma unroll
      for (int kk = 0; kk < 4; kk++)
        acc[r] += a[r][kk] * w[kk];
  }
  #pragma unroll
  for (int r = 0; r < 4; r++) {
    size_t grow = row0 + r0 + r;
    f4 x = acc[r];
    if (BIASMODE == 1) x += *(const f4*)&bias[j0];
    if (BIASMODE == 2) x += rs[grow] * (*(const f4*)&bias[j0]);
    if (BIASMODE == 3) x += rs[grow] * (*(const f4*)&bias[j0]) + *(const f4*)&bias2[j0];
    if (ACT) {
      #pragma unroll
      for (int c = 0; c < 4; c++) x[c] = lrelu(x[c]);
    }
    f4* op = (f4*)&out[grow * 128 + j0];
    if (ACC) x += *op;
    *op = x;
  }
}

// Gather form of message aggregation (edge set is symmetric, src-sorted):
// S[a] = sum over edges (a,c) of vlin[c] * lerp(table,d) * C.  No atomics.
__global__ __launch_bounds__(256) void edge_gather(
    const int* __restrict__ ei, const int* __restrict__ starts,
    const float* __restrict__ ed, const float* __restrict__ ec,
    const float* __restrict__ vlin, const float* __restrict__ table,
    float* __restrict__ S, float* __restrict__ deg, int E, int N) {
  int tid = threadIdx.x;
  int lane = tid & 31, grp = tid >> 5;
  int a = blockIdx.x * 8 + grp;
  if (a >= N) return;
  int s = starts[a], e_end = starts[a + 1];
  int j0 = lane * 4;
  const float sc = (float)(G_TAB - 1) / 5.0f;
  f4 acc = (f4)0.f;
  for (int e = s; e < e_end; e++) {
    int c = ei[E + e];
    float d = ed[e], cc = ec[e];
    float u = d * sc;
    int i0 = (int)u;
    if (i0 > G_TAB - 2) i0 = G_TAB - 2;
    float f = u - (float)i0;
    f4 t0 = *(const f4*)&table[(size_t)i0 * 128 + j0];
    f4 t1 = *(const f4*)&table[(size_t)i0 * 128 + 128 + j0];
    f4 vl = *(const f4*)&vlin[(size_t)c * 128 + j0];
    acc += vl * ((t0 + f * (t1 - t0)) * cc);
  }
  *(f4*)&S[(size_t)a * 128 + j0] = acc;
  if (lane == 0) deg[a] = (float)(e_end - s);
}

// per-atom u = lrelu(v@u_w1+b1)@u_w2+b2 ; per-graph mean (block = 256 atoms = 2 graphs)
__global__ __launch_bounds__(256, 1) void readout(
    const float* __restrict__ v, const float* __restrict__ uw1,
    const float* __restrict__ ub1, const float* __restrict__ uw2,
    const float* __restrict__ ub2, float* __restrict__ out) {
  __shared__ float wt[64 * 128];  // transposed u_w1: wt[m][k]
  __shared__ float red[256];
  int tid = threadIdx.x;
  for (int i = tid; i < 8192; i += 256) {
    int m = i >> 7, k = i & 127;
    wt[i] = uw1[k * 64 + m];
  }
  __syncthreads();
  size_t a = (size_t)blockIdx.x * 256 + tid;
  f4 row[32];
  #pragma unroll
  for (int i = 0; i < 32; i++) row[i] = *(const f4*)&v[a * 128 + i * 4];
  float pa = 0.f;
  for (int m = 0; m < 64; m++) {
    float dot = ub1[m];
    #pragma unroll
    for (int i = 0; i < 32; i++) {
      f4 w = *(f4*)&wt[m * 128 + i * 4];
      dot += row[i][0] * w[0] + row[i][1] * w[1] + row[i][2] * w[2] + row[i][3] * w[3];
    }
    pa += lrelu(dot) * uw2[m];
  }
  red[tid] = pa;
  __syncthreads();
  for (int s = 64; s > 0; s >>= 1) {
    if ((tid & 127) < s) red[tid] += red[tid + s];
    __syncthreads();
  }
  if ((tid & 127) == 0) out[blockIdx.x * 2 + (tid >> 7)] = red[tid] * (1.0f / 128.0f) + ub2[0];
}

extern "C" void kernel_launch(void* const* d_in, const int* in_sizes, int n_in,
                              void* d_out, int out_size, void* d_ws, size_t ws_size,
                              hipStream_t stream) {
  const int*   z     = (const int*)d_in[0];
  const float* pos   = (const float*)d_in[1];
  const int*   ei    = (const int*)d_in[3];
  const float* emb   = (const float*)d_in[4];
  const float* w_lin = (const float*)d_in[5];
  const float* mw1   = (const float*)d_in[6];
  const float* mb1   = (const float*)d_in[7];
  const float* mw2   = (const float*)d_in[8];
  const float* mb2   = (const float*)d_in[9];
  const float* mw3   = (const float*)d_in[10];
  const float* mb3   = (const float*)d_in[11];
  const float* loutw = (const float*)d_in[12];
  const float* loutb = (const float*)d_in[13];
  const float* vw1   = (const float*)d_in[14];
  const float* vb1   = (const float*)d_in[15];
  const float* vw2   = (const float*)d_in[16];
  const float* vb2   = (const float*)d_in[17];
  const float* uw1   = (const float*)d_in[18];
  const float* ub1   = (const float*)d_in[19];
  const float* uw2   = (const float*)d_in[20];
  const float* ub2   = (const float*)d_in[21];
  int N = in_sizes[0];
  int E = in_sizes[3] / 2;
  float* out = (float*)d_out;

  size_t off = 0;
  auto alloc = [&](size_t bytes) -> float* {
    float* p = (float*)((char*)d_ws + off);
    off += (bytes + 255) & ~(size_t)255;
    return p;
  };
  float* v     = alloc((size_t)N * 128 * 4);
  float* bufA  = alloc((size_t)N * 128 * 4);
  float* bufB  = alloc((size_t)N * 128 * 4);
  float* table = alloc((size_t)G_TAB * 128 * 4);
  float* loutI = alloc(128 * 128 * 4);
  float* Mbuf  = alloc(128 * 128 * 4);
  float* c1buf = alloc(128 * 4);
  float* deg   = alloc((size_t)N * 4);
  float* ed    = alloc((size_t)E * 4);
  float* ec    = alloc((size_t)E * 4);
  int*   starts = (int*)alloc((size_t)(N + 1) * 4);

  gather_emb<<<(N * 32 + 255) / 256, 256, 0, stream>>>(z, emb, v, N * 32);
  edge_geom<<<(E + 255) / 256, 256, 0, stream>>>(ei, pos, ed, ec, E);
  make_starts<<<(N + 256) / 256, 256, 0, stream>>>(ei, starts, E, N);

  for (int l = 0; l < 3; l++) {
    make_loutI<<<64, 256, 0, stream>>>(loutw + (size_t)l * 16384, loutI);
    // M = (lout_w + I) @ v_w1
    gemm128<0, 0, 0><<<4, 256, 0, stream>>>(loutI, vw1 + (size_t)l * 16384,
                                            nullptr, nullptr, nullptr, Mbuf);
    make_c1<<<1, 128, 0, stream>>>(loutb + (size_t)l * 128, vw1 + (size_t)l * 16384, c1buf);
    build_table<<<G_TAB / TG, 256, 0, stream>>>(
        mw1 + (size_t)l * 6400, mb1 + (size_t)l * 128,
        mw2 + (size_t)l * 16384, mb2 + (size_t)l * 128,
        mw3 + (size_t)l * 16384, mb3 + (size_t)l * 128, table);
    // vlin = v @ w_lin
    gemm128<0, 0, 0><<<N / 32, 256, 0, stream>>>(v, w_lin + (size_t)l * 16384,
                                                 nullptr, nullptr, nullptr, bufA);
    // S[a] = sum_nbr vlin[c] * W(d) * C   (gather, no atomics)
    edge_gather<<<(N + 7) / 8, 256, 0, stream>>>(ei, starts, ed, ec, bufA, table,
                                                 bufB, deg, E, N);
    // t = lrelu(S @ M + deg*c1 + v_b1)
    gemm128<1, 0, 3><<<N / 32, 256, 0, stream>>>(bufB, Mbuf, c1buf,
                                                 vb1 + (size_t)l * 128, deg, bufA);
    // v += t @ v_w2 + v_b2
    gemm128<0, 1, 1><<<N / 32, 256, 0, stream>>>(bufA, vw2 + (size_t)l * 16384,
                                                 vb2 + (size_t)l * 128, nullptr, nullptr, v);
  }
  readout<<<N / 256, 256, 0, stream>>>(v, uw1, ub1, uw2, ub2, out);
}

// Round 4
// 333.590 us; speedup vs baseline: 9.0362x; 1.5602x over previous
//
#include <hip/hip_runtime.h>

typedef float f4 __attribute__((ext_vector_type(4)));
typedef float f32x4 __attribute__((ext_vector_type(4)));
typedef short bf16x8 __attribute__((ext_vector_type(8)));
typedef short sh4 __attribute__((ext_vector_type(4)));

#define G_TAB 4096
#define TG 32
#define SWZ(row, b) ((b) ^ (((row) & 7) << 4))

__device__ __forceinline__ float lrelu(float x) { return x > 0.f ? x : 0.015f * x; }

__device__ __forceinline__ short f2bf(float x) {
  union { float f; unsigned u; } v; v.f = x;
  unsigned r = v.u + 0x7fff + ((v.u >> 16) & 1);
  return (short)(r >> 16);
}
__device__ __forceinline__ float bf2f(short h) {
  union { float f; unsigned u; } v; v.u = ((unsigned)(unsigned short)h) << 16;
  return v.f;
}

// v[i][:] = emb[z[i]][:]
__global__ __launch_bounds__(256) void gather_emb(const int* __restrict__ z,
    const float* __restrict__ emb, float* __restrict__ v, int nf4) {
  int i = blockIdx.x * 256 + threadIdx.x;
  if (i >= nf4) return;
  int a = i >> 5, s = i & 31;
  ((f4*)v)[i] = ((const f4*)emb)[z[a] * 32 + s];
}

__global__ __launch_bounds__(256) void edge_geom(const int* __restrict__ ei,
    const float* __restrict__ pos, float* __restrict__ ed, float* __restrict__ ec,
    int E) {
  int e = blockIdx.x * 256 + threadIdx.x;
  if (e >= E) return;
  int r = ei[e], c = ei[E + e];
  float dx = pos[3*r] - pos[3*c];
  float dy = pos[3*r+1] - pos[3*c+1];
  float dz = pos[3*r+2] - pos[3*c+2];
  float d = sqrtf(dx*dx + dy*dy + dz*dz);
  ed[e] = d;
  ec[e] = 0.5f * (cosf(d * 0.6283185307179586f) + 1.0f);
}

__global__ __launch_bounds__(256) void make_starts(const int* __restrict__ row,
    int* __restrict__ starts, int E, int N) {
  int i = blockIdx.x * 256 + threadIdx.x;
  if (i > N) return;
  int lo = 0, hi = E;
  while (lo < hi) { int mid = (lo + hi) >> 1; if (row[mid] < i) lo = mid + 1; else hi = mid; }
  starts[i] = lo;
}

// M_l = (lout_w_l + I) @ v_w1_l   (fp32, 12 small blocks)
__global__ __launch_bounds__(256) void gemm_prepM(const float* __restrict__ loutw,
    const float* __restrict__ vw1, float* __restrict__ Mall) {
  __shared__ float Ws[128 * 128];
  __shared__ float As[32 * 128];
  int tid = threadIdx.x;
  int l = blockIdx.y;
  const float* W = vw1 + (size_t)l * 16384;
  const float* A = loutw + (size_t)l * 16384;
  float* out = Mall + (size_t)l * 16384;
  #pragma unroll
  for (int i = 0; i < 16; i++) ((f4*)Ws)[tid + 256 * i] = ((const f4*)W)[tid + 256 * i];
  int row0 = blockIdx.x * 32;
  const f4* A4 = (const f4*)(A + (size_t)row0 * 128);
  #pragma unroll
  for (int i = 0; i < 4; i++) {
    int idx = tid + 256 * i;
    f4 x = A4[idx];
    int row = row0 + (idx >> 5);
    int k0 = (idx & 31) * 4;
    if (row >= k0 && row < k0 + 4) x[row - k0] += 1.0f;  // +I
    ((f4*)As)[idx] = x;
  }
  __syncthreads();
  int cg = tid & 31, rg = tid >> 5;
  int j0 = cg * 4, r0 = rg * 4;
  f4 acc[4];
  #pragma unroll
  for (int r = 0; r < 4; r++) acc[r] = (f4)0.f;
  for (int k = 0; k < 128; k += 4) {
    f4 a[4], w[4];
    #pragma unroll
    for (int r = 0; r < 4; r++) a[r] = *(f4*)&As[(r0 + r) * 128 + k];
    #pragma unroll
    for (int kk = 0; kk < 4; kk++) w[kk] = *(f4*)&Ws[(k + kk) * 128 + j0];
    #pragma unroll
    for (int r = 0; r < 4; r++)
      #pragma unroll
      for (int kk = 0; kk < 4; kk++)
        acc[r] += a[r][kk] * w[kk];
  }
  #pragma unroll
  for (int r = 0; r < 4; r++) *(f4*)&out[(size_t)(row0 + r0 + r) * 128 + j0] = acc[r];
}

// c1_l[j] = sum_k lout_b_l[k] * v_w1_l[k][j]
__global__ __launch_bounds__(128) void make_c1(const float* __restrict__ lball,
    const float* __restrict__ w1all, float* __restrict__ c1all) {
  int l = blockIdx.y;
  const float* lb = lball + (size_t)l * 128;
  const float* w1 = w1all + (size_t)l * 16384;
  int j = threadIdx.x;
  float s = 0.f;
  for (int k = 0; k < 128; k++) s += lb[k] * w1[k * 128 + j];
  c1all[l * 128 + j] = s;
}

// Convert 10 weight matrices to transposed bf16 hi/lo: dst[m][j][k], pitch 128.
// m 0-2: w_lin[l] (128x128); 3-5: Ms[l]; 6-8: v_w2[l]; 9: u_w1 (128x64).
__global__ __launch_bounds__(256) void convert_wt(const float* __restrict__ w_lin,
    const float* __restrict__ Ms, const float* __restrict__ vw2,
    const float* __restrict__ uw1, short* __restrict__ dhi, short* __restrict__ dlo) {
  int m = blockIdx.y;
  const float* src; int ncol;
  if (m < 3)      { src = w_lin + (size_t)m * 16384; ncol = 128; }
  else if (m < 6) { src = Ms + (size_t)(m - 3) * 16384; ncol = 128; }
  else if (m < 9) { src = vw2 + (size_t)(m - 6) * 16384; ncol = 128; }
  else            { src = uw1; ncol = 64; }
  int i = blockIdx.x * 256 + threadIdx.x;
  if (i >= 128 * ncol) return;
  int k, j;
  if (ncol == 128) { k = i >> 7; j = i & 127; } else { k = i >> 6; j = i & 63; }
  float x = src[i];
  short hi = f2bf(x);
  short lo = f2bf(x - bf2f(hi));
  size_t o = (size_t)m * 16384 + (size_t)j * 128 + k;
  dhi[o] = hi;
  dlo[o] = lo;
}

// Tabulate T_l(d) on G_TAB grid, all 3 layers in one launch (blockIdx.y = layer).
__global__ __launch_bounds__(256) void build_table(
    const float* __restrict__ w1a, const float* __restrict__ b1a,
    const float* __restrict__ w2a, const float* __restrict__ b2a,
    const float* __restrict__ w3a, const float* __restrict__ b3a,
    float* __restrict__ tables) {
  int l = blockIdx.y;
  const float* w1 = w1a + (size_t)l * 6400;
  const float* b1 = b1a + (size_t)l * 128;
  const float* w2 = w2a + (size_t)l * 16384;
  const float* b2 = b2a + (size_t)l * 128;
  const float* w3 = w3a + (size_t)l * 16384;
  const float* b3 = b3a + (size_t)l * 128;
  float* table = tables + (size_t)l * G_TAB * 128;
  __shared__ float wbuf[128 * 128];
  __shared__ float hA[TG * 128];
  __shared__ float hB[TG * 128];
  __shared__ float demb[TG * 52];
  int tid = threadIdx.x;
  int g0 = blockIdx.x * TG;
  const float delta = 5.0f / (G_TAB - 1);
  for (int i = tid; i < TG * 50; i += 256) {
    int p = i / 50, k = i - p * 50;
    float d = (g0 + p) * delta;
    float t = d - k * (5.0f / 49.0f);
    demb[p * 52 + k] = expf(-48.02f * t * t);
  }
  for (int i = tid; i < 1600; i += 256) ((f4*)wbuf)[i] = ((const f4*)w1)[i];
  __syncthreads();
  int cg = tid & 31, pl = tid >> 5;
  int j0 = cg * 4;
  f4 acc[4];
  {
    f4 bb = *(const f4*)&b1[j0];
    #pragma unroll
    for (int p = 0; p < 4; p++) acc[p] = (f4)0.f;
    for (int k = 0; k < 50; k++) {
      f4 w = *(f4*)&wbuf[k * 128 + j0];
      #pragma unroll
      for (int p = 0; p < 4; p++) acc[p] += demb[(pl * 4 + p) * 52 + k] * w;
    }
    #pragma unroll
    for (int p = 0; p < 4; p++) {
      f4 x = acc[p] + bb;
      #pragma unroll
      for (int c = 0; c < 4; c++) x[c] = lrelu(x[c]);
      *(f4*)&hA[(pl * 4 + p) * 128 + j0] = x;
    }
  }
  __syncthreads();
  for (int i = tid; i < 4096; i += 256) ((f4*)wbuf)[i] = ((const f4*)w2)[i];
  __syncthreads();
  {
    f4 bb = *(const f4*)&b2[j0];
    #pragma unroll
    for (int p = 0; p < 4; p++) acc[p] = (f4)0.f;
    for (int k = 0; k < 128; k++) {
      f4 w = *(f4*)&wbuf[k * 128 + j0];
      #pragma unroll
      for (int p = 0; p < 4; p++) acc[p] += hA[(pl * 4 + p) * 128 + k] * w;
    }
    #pragma unroll
    for (int p = 0; p < 4; p++) {
      f4 x = acc[p] + bb;
      #pragma unroll
      for (int c = 0; c < 4; c++) x[c] = lrelu(x[c]);
      *(f4*)&hB[(pl * 4 + p) * 128 + j0] = x;
    }
  }
  __syncthreads();
  for (int i = tid; i < 4096; i += 256) ((f4*)wbuf)[i] = ((const f4*)w3)[i];
  __syncthreads();
  {
    f4 bb = *(const f4*)&b3[j0];
    #pragma unroll
    for (int p = 0; p < 4; p++) acc[p] = (f4)0.f;
    for (int k = 0; k < 128; k++) {
      f4 w = *(f4*)&wbuf[k * 128 + j0];
      #pragma unroll
      for (int p = 0; p < 4; p++) acc[p] += hB[(pl * 4 + p) * 128 + k] * w;
    }
    #pragma unroll
    for (int p = 0; p < 4; p++)
      *(f4*)&table[(size_t)(g0 + pl * 4 + p) * 128 + j0] = acc[p] + bb;
  }
}

// ---- split-bf16 MFMA GEMM: out[Mx128] = op(A[Mx128] @ W[128x128] + bias) ----
template<int ACT, int ACC, int BIAS>
__global__ __launch_bounds__(256) void gemm_mfma(
    const float* __restrict__ A, const short* __restrict__ WhiT,
    const short* __restrict__ WloT, const float* __restrict__ bias,
    const float* __restrict__ bias2, const float* __restrict__ rs,
    float* __restrict__ out) {
  __shared__ __align__(16) short Ahi[16384];
  __shared__ __align__(16) short Alo[16384];
  __shared__ __align__(16) short Bhi[16384];
  __shared__ __align__(16) short Blo[16384];
  int tid = threadIdx.x;
  size_t row0 = (size_t)blockIdx.x * 128;
  const f4* A4 = (const f4*)(A + row0 * 128);
  #pragma unroll
  for (int s = 0; s < 16; s++) {
    int idx = tid + 256 * s;
    int row = idx >> 5, kq = idx & 31;
    f4 x = A4[idx];
    sh4 hi, lo;
    #pragma unroll
    for (int c = 0; c < 4; c++) {
      hi[c] = f2bf(x[c]);
      lo[c] = f2bf(x[c] - bf2f(hi[c]));
    }
    int b = row * 256 + SWZ(row, kq * 8);
    *(sh4*)((char*)Ahi + b) = hi;
    *(sh4*)((char*)Alo + b) = lo;
  }
  #pragma unroll
  for (int s = 0; s < 8; s++) {
    int idx8 = tid + 256 * s;
    int j = idx8 >> 4, ko = idx8 & 15;
    int b = j * 256 + SWZ(j, ko * 16);
    *(bf16x8*)((char*)Bhi + b) = ((const bf16x8*)WhiT)[idx8];
    *(bf16x8*)((char*)Blo + b) = ((const bf16x8*)WloT)[idx8];
  }
  __syncthreads();
  int l = tid & 63, wv = tid >> 6;
  int lr = l & 15, lk = l >> 4;
  f32x4 acc[2][8];
  #pragma unroll
  for (int fr = 0; fr < 2; fr++)
    #pragma unroll
    for (int fc = 0; fc < 8; fc++) acc[fr][fc] = (f32x4)0.f;
  #pragma unroll
  for (int ch = 0; ch < 4; ch++) {
    bf16x8 ah[2], al[2];
    #pragma unroll
    for (int fr = 0; fr < 2; fr++) {
      int arow = wv * 32 + fr * 16 + lr;
      int ab = arow * 256 + SWZ(arow, ch * 64 + lk * 16);
      ah[fr] = *(bf16x8*)((char*)Ahi + ab);
      al[fr] = *(bf16x8*)((char*)Alo + ab);
    }
    #pragma unroll
    for (int fc = 0; fc < 8; fc++) {
      int bcol = fc * 16 + lr;
      int bb = bcol * 256 + SWZ(bcol, ch * 64 + lk * 16);
      bf16x8 bh = *(bf16x8*)((char*)Bhi + bb);
      bf16x8 bl = *(bf16x8*)((char*)Blo + bb);
      #pragma unroll
      for (int fr = 0; fr < 2; fr++) {
        acc[fr][fc] = __builtin_amdgcn_mfma_f32_16x16x32_bf16(ah[fr], bh, acc[fr][fc], 0, 0, 0);
        acc[fr][fc] = __builtin_amdgcn_mfma_f32_16x16x32_bf16(al[fr], bh, acc[fr][fc], 0, 0, 0);
        acc[fr][fc] = __builtin_amdgcn_mfma_f32_16x16x32_bf16(ah[fr], bl, acc[fr][fc], 0, 0, 0);
      }
    }
  }
  #pragma unroll
  for (int fr = 0; fr < 2; fr++) {
    #pragma unroll
    for (int r = 0; r < 4; r++) {
      size_t row = row0 + wv * 32 + fr * 16 + lk * 4 + r;
      float rsv = (BIAS == 3) ? rs[row] : 0.f;
      #pragma unroll
      for (int fc = 0; fc < 8; fc++) {
        int col = fc * 16 + lr;
        float val = acc[fr][fc][r];
        if (BIAS == 1) val += bias[col];
        if (BIAS == 3) val += rsv * bias[col] + bias2[col];
        if (ACT) val = lrelu(val);
        float* op = &out[row * 128 + col];
        if (ACC) val += *op;
        *op = val;
      }
    }
  }
}

// readout: y[a] = sum_m lrelu((v @ u_w1)[a][m] + ub1[m]) * uw2[m]
__global__ __launch_bounds__(256) void readout_mfma(const float* __restrict__ v,
    const short* __restrict__ BhT, const short* __restrict__ BlT,
    const float* __restrict__ ub1, const float* __restrict__ uw2,
    float* __restrict__ y) {
  __shared__ __align__(16) short Ahi[16384];
  __shared__ __align__(16) short Alo[16384];
  __shared__ __align__(16) short Bh[8192];
  __shared__ __align__(16) short Bl[8192];
  int tid = threadIdx.x;
  size_t row0 = (size_t)blockIdx.x * 128;
  const f4* A4 = (const f4*)(v + row0 * 128);
  #pragma unroll
  for (int s = 0; s < 16; s++) {
    int idx = tid + 256 * s;
    int row = idx >> 5, kq = idx & 31;
    f4 x = A4[idx];
    sh4 hi, lo;
    #pragma unroll
    for (int c = 0; c < 4; c++) {
      hi[c] = f2bf(x[c]);
      lo[c] = f2bf(x[c] - bf2f(hi[c]));
    }
    int b = row * 256 + SWZ(row, kq * 8);
    *(sh4*)((char*)Ahi + b) = hi;
    *(sh4*)((char*)Alo + b) = lo;
  }
  // FIX (R3 bug): u_w1^T is 64 rows x 16 groups = 1024 groups -> 4 stages, not 2.
  #pragma unroll
  for (int s = 0; s < 4; s++) {
    int idx8 = tid + 256 * s;
    int j = idx8 >> 4, ko = idx8 & 15;
    int b = j * 256 + SWZ(j, ko * 16);
    *(bf16x8*)((char*)Bh + b) = ((const bf16x8*)BhT)[idx8];
    *(bf16x8*)((char*)Bl + b) = ((const bf16x8*)BlT)[idx8];
  }
  __syncthreads();
  int l = tid & 63, wv = tid >> 6;
  int lr = l & 15, lk = l >> 4;
  float b1v[4], w2v[4];
  #pragma unroll
  for (int fc = 0; fc < 4; fc++) {
    int col = fc * 16 + lr;
    b1v[fc] = ub1[col];
    w2v[fc] = uw2[col];
  }
  f32x4 acc[2][4];
  #pragma unroll
  for (int fr = 0; fr < 2; fr++)
    #pragma unroll
    for (int fc = 0; fc < 4; fc++) acc[fr][fc] = (f32x4)0.f;
  #pragma unroll
  for (int ch = 0; ch < 4; ch++) {
    bf16x8 ah[2], al[2];
    #pragma unroll
    for (int fr = 0; fr < 2; fr++) {
      int arow = wv * 32 + fr * 16 + lr;
      int ab = arow * 256 + SWZ(arow, ch * 64 + lk * 16);
      ah[fr] = *(bf16x8*)((char*)Ahi + ab);
      al[fr] = *(bf16x8*)((char*)Alo + ab);
    }
    #pragma unroll
    for (int fc = 0; fc < 4; fc++) {
      int bcol = fc * 16 + lr;
      int bb = bcol * 256 + SWZ(bcol, ch * 64 + lk * 16);
      bf16x8 bh = *(bf16x8*)((char*)Bh + bb);
      bf16x8 bl = *(bf16x8*)((char*)Bl + bb);
      #pragma unroll
      for (int fr = 0; fr < 2; fr++) {
        acc[fr][fc] = __builtin_amdgcn_mfma_f32_16x16x32_bf16(ah[fr], bh, acc[fr][fc], 0, 0, 0);
        acc[fr][fc] = __builtin_amdgcn_mfma_f32_16x16x32_bf16(al[fr], bh, acc[fr][fc], 0, 0, 0);
        acc[fr][fc] = __builtin_amdgcn_mfma_f32_16x16x32_bf16(ah[fr], bl, acc[fr][fc], 0, 0, 0);
      }
    }
  }
  #pragma unroll
  for (int fr = 0; fr < 2; fr++) {
    #pragma unroll
    for (int r = 0; r < 4; r++) {
      float p = 0.f;
      #pragma unroll
      for (int fc = 0; fc < 4; fc++)
        p += lrelu(acc[fr][fc][r] + b1v[fc]) * w2v[fc];
      p += __shfl_xor(p, 1);
      p += __shfl_xor(p, 2);
      p += __shfl_xor(p, 4);
      p += __shfl_xor(p, 8);
      if (lr == 0) y[row0 + wv * 32 + fr * 16 + lk * 4 + r] = p;
    }
  }
}

__global__ __launch_bounds__(256) void graph_mean(const float* __restrict__ y,
    const float* __restrict__ ub2, float* __restrict__ out) {
  __shared__ float red[256];
  int tid = threadIdx.x;
  red[tid] = y[blockIdx.x * 256 + tid];
  __syncthreads();
  for (int s = 64; s > 0; s >>= 1) {
    if ((tid & 127) < s) red[tid] += red[tid + s];
    __syncthreads();
  }
  if ((tid & 127) == 0)
    out[blockIdx.x * 2 + (tid >> 7)] = red[tid] * (1.0f / 128.0f) + ub2[0];
}

// S[a] = sum over edges (a,c) of vlin[c] * lerp(table,d) * C.  No atomics.
__global__ __launch_bounds__(256) void edge_gather(
    const int* __restrict__ ei, const int* __restrict__ starts,
    const float* __restrict__ ed, const float* __restrict__ ec,
    const float* __restrict__ vlin, const float* __restrict__ table,
    float* __restrict__ S, float* __restrict__ deg, int E, int N) {
  int tid = threadIdx.x;
  int lane = tid & 31, grp = tid >> 5;
  int a = blockIdx.x * 8 + grp;
  if (a >= N) return;
  int s = starts[a], e_end = starts[a + 1];
  int j0 = lane * 4;
  const float sc = (float)(G_TAB - 1) / 5.0f;
  f4 acc = (f4)0.f;
  for (int e = s; e < e_end; e++) {
    int c = ei[E + e];
    float d = ed[e], cc = ec[e];
    float u = d * sc;
    int i0 = (int)u;
    if (i0 > G_TAB - 2) i0 = G_TAB - 2;
    float f = u - (float)i0;
    f4 t0 = *(const f4*)&table[(size_t)i0 * 128 + j0];
    f4 t1 = *(const f4*)&table[(size_t)i0 * 128 + 128 + j0];
    f4 vl = *(const f4*)&vlin[(size_t)c * 128 + j0];
    acc += vl * ((t0 + f * (t1 - t0)) * cc);
  }
  *(f4*)&S[(size_t)a * 128 + j0] = acc;
  if (lane == 0) deg[a] = (float)(e_end - s);
}

extern "C" void kernel_launch(void* const* d_in, const int* in_sizes, int n_in,
                              void* d_out, int out_size, void* d_ws, size_t ws_size,
                              hipStream_t stream) {
  const int*   z     = (const int*)d_in[0];
  const float* pos   = (const float*)d_in[1];
  const int*   ei    = (const int*)d_in[3];
  const float* emb   = (const float*)d_in[4];
  const float* w_lin = (const float*)d_in[5];
  const float* mw1   = (const float*)d_in[6];
  const float* mb1   = (const float*)d_in[7];
  const float* mw2   = (const float*)d_in[8];
  const float* mb2   = (const float*)d_in[9];
  const float* mw3   = (const float*)d_in[10];
  const float* mb3   = (const float*)d_in[11];
  const float* loutw = (const float*)d_in[12];
  const float* loutb = (const float*)d_in[13];
  const float* vw1   = (const float*)d_in[14];
  const float* vb1   = (const float*)d_in[15];
  const float* vw2   = (const float*)d_in[16];
  const float* vb2   = (const float*)d_in[17];
  const float* uw1   = (const float*)d_in[18];
  const float* ub1   = (const float*)d_in[19];
  const float* uw2   = (const float*)d_in[20];
  const float* ub2   = (const float*)d_in[21];
  int N = in_sizes[0];
  int E = in_sizes[3] / 2;
  float* out = (float*)d_out;

  size_t off = 0;
  auto alloc = [&](size_t bytes) -> void* {
    void* p = (char*)d_ws + off;
    off += (bytes + 255) & ~(size_t)255;
    return p;
  };
  float* v      = (float*)alloc((size_t)N * 128 * 4);
  float* bufA   = (float*)alloc((size_t)N * 128 * 4);
  float* bufB   = (float*)alloc((size_t)N * 128 * 4);
  float* tables = (float*)alloc((size_t)3 * G_TAB * 128 * 4);
  float* Ms     = (float*)alloc(3 * 16384 * 4);
  float* c1s    = (float*)alloc(3 * 128 * 4);
  short* whiT   = (short*)alloc(10 * 16384 * 2);
  short* wloT   = (short*)alloc(10 * 16384 * 2);
  float* deg    = (float*)alloc((size_t)N * 4);
  float* ed     = (float*)alloc((size_t)E * 4);
  float* ec     = (float*)alloc((size_t)E * 4);
  int*   starts = (int*)alloc((size_t)(N + 1) * 4);
  float* y      = (float*)alloc((size_t)N * 4);

  gather_emb<<<(N * 32 + 255) / 256, 256, 0, stream>>>(z, emb, v, N * 32);
  edge_geom<<<(E + 255) / 256, 256, 0, stream>>>(ei, pos, ed, ec, E);
  make_starts<<<(N + 256) / 256, 256, 0, stream>>>(ei, starts, E, N);
  gemm_prepM<<<dim3(4, 3), 256, 0, stream>>>(loutw, vw1, Ms);
  make_c1<<<dim3(1, 3), 128, 0, stream>>>(loutb, vw1, c1s);
  build_table<<<dim3(G_TAB / TG, 3), 256, 0, stream>>>(mw1, mb1, mw2, mb2, mw3, mb3, tables);
  convert_wt<<<dim3(64, 10), 256, 0, stream>>>(w_lin, Ms, vw2, uw1, whiT, wloT);

  for (int l = 0; l < 3; l++) {
    gemm_mfma<0, 0, 0><<<N / 128, 256, 0, stream>>>(
        v, whiT + (size_t)l * 16384, wloT + (size_t)l * 16384,
        nullptr, nullptr, nullptr, bufA);
    edge_gather<<<(N + 7) / 8, 256, 0, stream>>>(ei, starts, ed, ec, bufA,
                                                 tables + (size_t)l * G_TAB * 128,
                                                 bufB, deg, E, N);
    gemm_mfma<1, 0, 3><<<N / 128, 256, 0, stream>>>(
        bufB, whiT + (size_t)(3 + l) * 16384, wloT + (size_t)(3 + l) * 16384,
        c1s + (size_t)l * 128, vb1 + (size_t)l * 128, deg, bufA);
    gemm_mfma<0, 1, 1><<<N / 128, 256, 0, stream>>>(
        bufA, whiT + (size_t)(6 + l) * 16384, wloT + (size_t)(6 + l) * 16384,
        vb2 + (size_t)l * 128, nullptr, nullptr, v);
  }
  readout_mfma<<<N / 128, 256, 0, stream>>>(v, whiT + 9 * 16384, wloT + 9 * 16384,
                                            ub1, uw2, y);
  graph_mean<<<N / 256, 256, 0, stream>>>(y, ub2, out);
}